// Round 13
// baseline (1066.658 us; speedup 1.0000x reference)
//
#include <hip/hip_runtime.h>

#define BB 4096
#define TD 5000
#define NN 200000
#define EE 6400000
#define NBK 782  // ceil(NN/256)
#define WS_NEED 62481928ull

// wave-local edge-dtype detect: int64 -> high words all zero.
// Each lane reads one of 64 distinct high-words; OR-reduce across the wave.
__device__ __forceinline__ int detect_i64(const int* __restrict__ e) {
    int v = e[2 * (threadIdx.x & 63) + 1];
#pragma unroll
    for (int off = 32; off >= 1; off >>= 1) v |= __shfl_xor(v, off, 64);
    return v == 0;
}

// ================= device roles =================
// rank: 8 edges/thread; deg starts at 0 (memset); pack (rank<<18 | dst).
__device__ void role_rank(int rid, int tid, const int* __restrict__ edge,
                          unsigned int* __restrict__ deg, unsigned int* __restrict__ rnkpack) {
    int f = detect_i64(edge);
    int base = rid * 2048 + tid;
    int d[8];
#pragma unroll
    for (int k = 0; k < 8; k++) {
        int e = base + k * 256;
        d[k] = f ? edge[2 * (EE + e)] : edge[EE + e];
    }
    unsigned int rr[8];
#pragma unroll
    for (int k = 0; k < 8; k++) rr[k] = atomicAdd(&deg[d[k]], 1u);
#pragma unroll
    for (int k = 0; k < 8; k++) rnkpack[base + k * 256] = (rr[k] << 18) | (unsigned int)d[k];
}

__device__ void role_enc(int row, int tid, const float* __restrict__ text,
                         const float* __restrict__ We1, const float* __restrict__ be1,
                         const float* __restrict__ We2, const float* __restrict__ be2,
                         float* __restrict__ z_text) {
    __shared__ float red[8][256];
    __shared__ float t1[8];
    const float4* xrow = (const float4*)(text + (size_t)row * TD);  // 1250 vec4
    float acc[8];
#pragma unroll
    for (int j = 0; j < 8; j++) acc[j] = 0.f;
    for (int v = tid; v < 1250; v += 256) {
        float4 xv = xrow[v];
        const float4* w = (const float4*)(We1 + (size_t)v * 32);
        float xc[4] = {xv.x, xv.y, xv.z, xv.w};
#pragma unroll
        for (int c = 0; c < 4; c++) {
            float4 wa = w[c * 2], wb = w[c * 2 + 1];
            acc[0] += xc[c] * wa.x; acc[1] += xc[c] * wa.y;
            acc[2] += xc[c] * wa.z; acc[3] += xc[c] * wa.w;
            acc[4] += xc[c] * wb.x; acc[5] += xc[c] * wb.y;
            acc[6] += xc[c] * wb.z; acc[7] += xc[c] * wb.w;
        }
    }
#pragma unroll
    for (int j = 0; j < 8; j++) red[j][tid] = acc[j];
    __syncthreads();
    for (int s = 128; s > 0; s >>= 1) {
        if (tid < s) {
#pragma unroll
            for (int j = 0; j < 8; j++) red[j][tid] += red[j][tid + s];
        }
        __syncthreads();
    }
    if (tid < 8) t1[tid] = fmaxf(red[tid][0] + be1[tid], 0.f);
    __syncthreads();
    if (tid < 4) {
        float z = be2[tid];
#pragma unroll
        for (int k = 0; k < 8; k++) z += t1[k] * We2[k * 4 + tid];
        z_text[row * 4 + tid] = fmaxf(z, 0.f);
    }
}

__device__ void role_decode(int row, int tid, const float* __restrict__ zsrc, int zstride,
                            const float* __restrict__ Wd1, const float* __restrict__ bd1,
                            const float* __restrict__ Wd2, const float* __restrict__ bd2,
                            float* __restrict__ xhat) {
    float zz[4];
#pragma unroll
    for (int j = 0; j < 4; j++) zz[j] = zsrc[row * zstride + j];
    float t[8];
#pragma unroll
    for (int k = 0; k < 8; k++) {
        float s = bd1[k];
#pragma unroll
        for (int j = 0; j < 4; j++) s += zz[j] * Wd1[j * 8 + k];
        t[k] = fmaxf(s, 0.f);
    }
    float4* orow = (float4*)(xhat + (size_t)row * TD);  // 1250 vec4
    for (int c4 = tid; c4 < 1250; c4 += 256) {
        float4 s = *(const float4*)(bd2 + c4 * 4);
#pragma unroll
        for (int k = 0; k < 8; k++) {
            float4 w = *(const float4*)(Wd2 + (size_t)k * TD + c4 * 4);
            s.x += t[k] * w.x; s.y += t[k] * w.y;
            s.z += t[k] * w.z; s.w += t[k] * w.w;
        }
        s.x = 1.f / (1.f + expf(-s.x));
        s.y = 1.f / (1.f + expf(-s.y));
        s.z = 1.f / (1.f + expf(-s.z));
        s.w = 1.f / (1.f + expf(-s.w));
        orow[c4] = s;
    }
}

__device__ void role_place(int pid, int tid, const int* __restrict__ edge,
                           const unsigned int* __restrict__ indptr,
                           const unsigned int* __restrict__ rnkpack, int* __restrict__ csr) {
    int f = detect_i64(edge);
    int base = pid * 1024 + tid;
    int s[4];
    unsigned int p[4];
#pragma unroll
    for (int k = 0; k < 4; k++) {
        int e = base + k * 256;
        s[k] = f ? edge[2 * e] : edge[e];
        p[k] = rnkpack[e];
    }
    unsigned int ip[4];
#pragma unroll
    for (int k = 0; k < 4; k++) ip[k] = indptr[p[k] & 0x3FFFFu];
#pragma unroll
    for (int k = 0; k < 4; k++) csr[ip[k] + (p[k] >> 18)] = s[k];
}

__device__ void role_g1(int gid, int tid, const unsigned int* __restrict__ indptr,
                        const int* __restrict__ csr, const float* __restrict__ h0g,
                        const float* __restrict__ dinv, const float* __restrict__ bg1,
                        const float* __restrict__ Wg2, float* __restrict__ h2g) {
    __shared__ float W[32];
    __shared__ float b1[8];
    __shared__ float h1s[4][8];
    if (tid < 32) W[tid] = Wg2[tid];
    if (tid < 8) b1[tid] = bg1[tid];
    __syncthreads();
    int wid = tid >> 6, lane = tid & 63;
    int i = gid * 4 + wid;
    if (i < NN) {
        int beg = indptr[i], end = indptr[i + 1];
        int f = lane & 7;
        float a = 0.f;
        for (int k = beg + (lane >> 3); k < end; k += 8)
            a += h0g[(size_t)csr[k] * 8 + f];
        a += __shfl_xor(a, 8, 64);
        a += __shfl_xor(a, 16, 64);
        a += __shfl_xor(a, 32, 64);
        if (lane < 8) {
            float di = dinv[i];
            h1s[wid][f] = fmaxf(di * (a + h0g[(size_t)i * 8 + f]) + b1[f], 0.f);
        }
    }
    __syncthreads();
    if (i < NN && lane < 4) {
        float di = dinv[i];
        float s = 0.f;
#pragma unroll
        for (int k = 0; k < 8; k++) s += h1s[wid][k] * W[k * 4 + lane];
        h2g[(size_t)i * 4 + lane] = di * s;
    }
}

// ================= kernels =================
// fat1: rank (3125) || encode (4096); grid 7221. Dynamic LDS = ws-tier probe.
__global__ __launch_bounds__(256) void k_fat1(
    const int* __restrict__ edge, unsigned int* __restrict__ deg,
    unsigned int* __restrict__ rnkpack, const float* __restrict__ text,
    const float* __restrict__ We1, const float* __restrict__ be1,
    const float* __restrict__ We2, const float* __restrict__ be2,
    float* __restrict__ z_text)
{
    int bid = blockIdx.x, tid = threadIdx.x;
    if (bid < 6250) {
        if (bid & 1) role_enc(bid >> 1, tid, text, We1, be1, We2, be2, z_text);
        else role_rank(bid >> 1, tid, edge, deg, rnkpack);
    } else {
        role_enc(3125 + (bid - 6250), tid, text, We1, be1, We2, be2, z_text);
    }
}

// node pass: blocks 0..NBK-1 = dinv + batch boundaries + GCN1 matmul;
// block NBK = single-block chunked exclusive scan deg -> indptr.
__global__ __launch_bounds__(256) void k_node(
    const unsigned int* __restrict__ deg, const int* __restrict__ batch,
    const int* __restrict__ edge, const float* __restrict__ nodex,
    const float* __restrict__ Wg1, float* __restrict__ dinv,
    unsigned int* __restrict__ bnd, float* __restrict__ h0g,
    unsigned int* __restrict__ indptr)
{
    int bid = blockIdx.x, tid = threadIdx.x;
    if (bid == NBK) {
        // ---- scan role ----
        __shared__ unsigned int ps[256];
        const int CH = 782;  // ceil(NN/256)
        int lo = tid * CH, hi = min(lo + CH, NN);
        unsigned int s = 0;
        for (int i = lo; i < hi; i++) s += deg[i];
        ps[tid] = s;
        __syncthreads();
        for (int off = 1; off < 256; off <<= 1) {
            unsigned int v = (tid >= off) ? ps[tid - off] : 0u;
            __syncthreads();
            ps[tid] += v;
            __syncthreads();
        }
        unsigned int run = (tid == 0) ? 0u : ps[tid - 1];
        for (int i = lo; i < hi; i++) { indptr[i] = run; run += deg[i]; }
        if (tid == 255) indptr[NN] = run;  // == EE
        return;
    }
    // ---- dinv + bnd + mm role ----
    __shared__ float W[1024];
    for (int i = tid; i < 1024; i += 256) W[i] = Wg1[i];
    int i = bid * 256 + tid;
    int f = detect_i64(edge);
    float di = 0.f;
    if (i < NN) {
        unsigned int u = deg[i];
        di = rsqrtf((float)(u + 1u));  // +1 self-loop
        dinv[i] = di;
        int b = f ? batch[2 * i] : batch[i];
        int bp = (i == 0) ? -1 : (f ? batch[2 * (i - 1)] : batch[i - 1]);
        for (int bb = bp + 1; bb <= b; bb++) bnd[bb] = (unsigned int)i;
        if (i == NN - 1)
            for (int bb = b + 1; bb <= BB; bb++) bnd[bb] = (unsigned int)NN;
    }
    __syncthreads();
    if (i >= NN) return;
    const float4* xr = (const float4*)(nodex + (size_t)i * 128);
    float acc[8];
#pragma unroll
    for (int j = 0; j < 8; j++) acc[j] = 0.f;
#pragma unroll 8
    for (int c2 = 0; c2 < 32; c2++) {
        float4 v = xr[c2];
        const float* wr = &W[c2 * 32];
#pragma unroll
        for (int j = 0; j < 8; j++)
            acc[j] += v.x * wr[j] + v.y * wr[8 + j] + v.z * wr[16 + j] + v.w * wr[24 + j];
    }
    float* o = h0g + (size_t)i * 8;
#pragma unroll
    for (int j = 0; j < 8; j++) o[j] = di * acc[j];
}

// tier B: place alone (6250)
__global__ __launch_bounds__(256) void k_place(
    const int* __restrict__ edge, const unsigned int* __restrict__ indptr,
    const unsigned int* __restrict__ rnkpack, int* __restrict__ csr)
{
    role_place(blockIdx.x, threadIdx.x, edge, indptr, rnkpack, csr);
}

// tier A: place (6250) || decode (4096); grid 10346
__global__ __launch_bounds__(256) void k_place_dec(
    const int* __restrict__ edge, const unsigned int* __restrict__ indptr,
    const unsigned int* __restrict__ rnkpack, int* __restrict__ csr,
    const float* __restrict__ z_text,
    const float* __restrict__ Wd1, const float* __restrict__ bd1,
    const float* __restrict__ Wd2, const float* __restrict__ bd2,
    float* __restrict__ xhat)
{
    int bid = blockIdx.x, tid = threadIdx.x;
    if (bid < 8192) {
        if (bid & 1) role_decode(bid >> 1, tid, z_text, 4, Wd1, bd1, Wd2, bd2, xhat);
        else role_place(bid >> 1, tid, edge, indptr, rnkpack, csr);
    } else {
        role_place(4096 + (bid - 8192), tid, edge, indptr, rnkpack, csr);
    }
}

__global__ __launch_bounds__(256) void k_g1(
    const unsigned int* __restrict__ indptr, const int* __restrict__ csr,
    const float* __restrict__ h0g, const float* __restrict__ dinv,
    const float* __restrict__ bg1, const float* __restrict__ Wg2,
    float* __restrict__ h2g)
{
    role_g1(blockIdx.x, threadIdx.x, indptr, csr, h0g, dinv, bg1, Wg2, h2g);
}

// standalone decode (tier B, runs last; reads out_z stride 8)
__global__ __launch_bounds__(256) void k_dec(
    const float* __restrict__ zsrc,
    const float* __restrict__ Wd1, const float* __restrict__ bd1,
    const float* __restrict__ Wd2, const float* __restrict__ bd2,
    float* __restrict__ xhat)
{
    role_decode(blockIdx.x, threadIdx.x, zsrc, 8, Wd1, bd1, Wd2, bd2, xhat);
}

__global__ __launch_bounds__(256) void k_gather2(
    const unsigned int* __restrict__ indptr, const int* __restrict__ csr_src,
    const float* __restrict__ h2g, const float* __restrict__ dinv,
    const float* __restrict__ bg2, float* __restrict__ h2f)
{
    __shared__ float b2[4];
    int tid = threadIdx.x;
    if (tid < 4) b2[tid] = bg2[tid];
    __syncthreads();
    int wid = tid >> 6, lane = tid & 63;
    int i = blockIdx.x * 4 + wid;
    if (i >= NN) return;
    int beg = indptr[i], end = indptr[i + 1];
    int f = lane & 3;
    float a = 0.f;
    for (int k = beg + (lane >> 2); k < end; k += 16)
        a += h2g[(size_t)csr_src[k] * 4 + f];
    a += __shfl_xor(a, 4, 64);
    a += __shfl_xor(a, 8, 64);
    a += __shfl_xor(a, 16, 64);
    a += __shfl_xor(a, 32, 64);
    if (lane < 4) {
        float di = dinv[i];
        h2f[(size_t)i * 4 + f] = di * (a + h2g[(size_t)i * 4 + f]) + b2[f];
    }
}

__global__ __launch_bounds__(256) void k_final(
    const float* __restrict__ h2f, const unsigned int* __restrict__ bnd,
    const float* __restrict__ z_text, const float* __restrict__ Wc,
    const float* __restrict__ bc, float* __restrict__ out_logits,
    float* __restrict__ out_z)
{
    __shared__ float red[256][4];
    int g = blockIdx.x, tid = threadIdx.x;
    int lo = bnd[g], hi = bnd[g + 1];
    float a0 = 0.f, a1 = 0.f, a2 = 0.f, a3 = 0.f;
    for (int i = lo + tid; i < hi; i += 256) {
        float4 v = *(const float4*)(h2f + (size_t)i * 4);
        a0 += v.x; a1 += v.y; a2 += v.z; a3 += v.w;
    }
    red[tid][0] = a0; red[tid][1] = a1; red[tid][2] = a2; red[tid][3] = a3;
    __syncthreads();
    for (int s = 128; s > 0; s >>= 1) {
        if (tid < s) {
            red[tid][0] += red[tid + s][0]; red[tid][1] += red[tid + s][1];
            red[tid][2] += red[tid + s][2]; red[tid][3] += red[tid + s][3];
        }
        __syncthreads();
    }
    if (tid == 0) {
        float c = (float)(hi - lo);
        c = fmaxf(c, 1.f);
        float z8[8];
#pragma unroll
        for (int j = 0; j < 4; j++) z8[j] = z_text[g * 4 + j];
#pragma unroll
        for (int j = 0; j < 4; j++) z8[4 + j] = red[0][j] / c;
        float l = bc[0];
#pragma unroll
        for (int k = 0; k < 8; k++) l += z8[k] * Wc[k];
        out_logits[g] = l;
#pragma unroll
        for (int k = 0; k < 8; k++) out_z[g * 8 + k] = z8[k];
    }
}

extern "C" void kernel_launch(void* const* d_in, const int* in_sizes, int n_in,
                              void* d_out, int out_size, void* d_ws, size_t ws_size,
                              hipStream_t stream) {
    const float* text  = (const float*)d_in[0];
    const float* nodex = (const float*)d_in[1];
    const int* edge    = (const int*)d_in[2];
    const int* batch   = (const int*)d_in[3];
    const float* We1 = (const float*)d_in[4];
    const float* be1 = (const float*)d_in[5];
    const float* We2 = (const float*)d_in[6];
    const float* be2 = (const float*)d_in[7];
    const float* Wd1 = (const float*)d_in[8];
    const float* bd1 = (const float*)d_in[9];
    const float* Wd2 = (const float*)d_in[10];
    const float* bd2 = (const float*)d_in[11];
    const float* Wg1 = (const float*)d_in[12];
    const float* bg1 = (const float*)d_in[13];
    const float* Wg2 = (const float*)d_in[14];
    const float* bg2 = (const float*)d_in[15];
    const float* Wc  = (const float*)d_in[16];
    const float* bc  = (const float*)d_in[17];

    float* out_xhat   = (float*)d_out;
    float* out_logits = out_xhat + (size_t)BB * TD;
    float* out_z      = out_logits + BB;

    const bool use_ws = (ws_size >= WS_NEED);

    float *h0g, *h2g, *h2f, *dinv, *z_text;
    unsigned int *deg, *indptr, *rnkpack, *bnd;
    int *csr;

    if (use_ws) {
        // Tier A: everything place/gather-live in d_ws; deg (dead early) in d_out.
        char* w = (char*)d_ws;
        rnkpack = (unsigned int*)(w + 0);          // 25,600,000 (dead after place)
        csr     = (int*)(w + 25600000);            // 25,600,000
        h0g     = (float*)(w + 51200000);          //  6,400,000
        h2f     = h0g;                             // alias (h0g dead after g1)
        h2g     = (float*)(w + 57600000);          //  3,200,000
        dinv    = (float*)(w + 60800000);          //    800,000
        indptr  = (unsigned int*)(w + 61600000);   //    800,004
        z_text  = (float*)(w + 62400004);          //     65,536
        bnd     = (unsigned int*)(w + 62465540);   //     16,388 -> 62,481,928
        deg     = (unsigned int*)d_out;            // dead after k_node
    } else {
        // Tier B: everything in d_out x_hat region; decode runs last.
        char* o = (char*)d_out;
        h0g     = (float*)(o + 0);
        h2g     = (float*)(o + 6400000);
        h2f     = (float*)(o + 9600000);
        dinv    = (float*)(o + 12800000);
        deg     = (unsigned int*)(o + 13600000);
        indptr  = (unsigned int*)(o + 14400000);
        rnkpack = (unsigned int*)(o + 15200004);
        csr     = (int*)(o + 40800004);
        z_text  = (float*)(o + 66400008);
        bnd     = (unsigned int*)(o + 66465544);   // ends 66,481,932 < 81,920,000
    }

    hipMemsetAsync(deg, 0, NN * sizeof(unsigned int), stream);

    // dynamic-LDS probe: tier A -> +1024 B visible in LDS_Block_Size
    k_fat1<<<7221, 256, use_ws ? 1024 : 0, stream>>>(edge, deg, rnkpack,
                                                     text, We1, be1, We2, be2, z_text);
    k_node<<<NBK + 1, 256, 0, stream>>>(deg, batch, edge, nodex, Wg1,
                                        dinv, bnd, h0g, indptr);

    if (use_ws) {
        k_place_dec<<<10346, 256, 0, stream>>>(edge, indptr, rnkpack, csr,
                                               z_text, Wd1, bd1, Wd2, bd2, out_xhat);
    } else {
        k_place<<<6250, 256, 0, stream>>>(edge, indptr, rnkpack, csr);
    }

    k_g1<<<(NN + 3) / 4, 256, 0, stream>>>(indptr, csr, h0g, dinv, bg1, Wg2, h2g);
    k_gather2<<<(NN + 3) / 4, 256, 0, stream>>>(indptr, csr, h2g, dinv, bg2, h2f);
    k_final<<<BB, 256, 0, stream>>>(h2f, bnd, z_text, Wc, bc, out_logits, out_z);

    if (!use_ws) {
        k_dec<<<BB, 256, 0, stream>>>(out_z, Wd1, bd1, Wd2, bd2, out_xhat);
    }
}

// Round 14
// 744.379 us; speedup vs baseline: 1.4330x; 1.4330x over previous
//
#include <hip/hip_runtime.h>

#define BB 4096
#define TD 5000
#define NN 200000
#define EE 6400000
#define NBK 782  // ceil(NN/256)
#define WS_NEED 40081932ull

// ---------------- init: deg=1 everywhere; block 0 also detects edge dtype ----------------
__global__ void k_init(const int* __restrict__ e, unsigned int* __restrict__ deg,
                       int* __restrict__ flag) {
    int i = blockIdx.x * 256 + threadIdx.x;
    if (i < NN) deg[i] = 1u;  // self loop
    if (blockIdx.x == 0) {
        __shared__ int r[256];
        int tid = threadIdx.x;
        int acc = 0;
        for (int k = tid; k < 4096; k += 256) acc |= e[2 * k + 1];
        r[tid] = acc;
        __syncthreads();
        for (int s = 128; s > 0; s >>= 1) {
            if (tid < s) r[tid] |= r[tid + s];
            __syncthreads();
        }
        if (tid == 0) *flag = (r[0] == 0) ? 1 : 0;
    }
}

// ================= device roles (round-9 proven bodies) =================
__device__ void role_rank(int rid, int tid, const int* __restrict__ edge,
                          const int* __restrict__ flag, unsigned int* __restrict__ deg,
                          unsigned int* __restrict__ rnk) {
    int f = *flag;
    int base = rid * 2048 + tid;
    int d[8];
#pragma unroll
    for (int k = 0; k < 8; k++) {
        int e = base + k * 256;
        d[k] = f ? edge[2 * (EE + e)] : edge[EE + e];
    }
    unsigned int rr[8];
#pragma unroll
    for (int k = 0; k < 8; k++) rr[k] = atomicAdd(&deg[d[k]], 1u);
#pragma unroll
    for (int k = 0; k < 8; k++) rnk[base + k * 256] = rr[k];
}

__device__ void role_enc(int row, int tid, const float* __restrict__ text,
                         const float* __restrict__ We1, const float* __restrict__ be1,
                         const float* __restrict__ We2, const float* __restrict__ be2,
                         float* __restrict__ z_text) {
    __shared__ float red[8][256];
    __shared__ float t1[8];
    const float4* xrow = (const float4*)(text + (size_t)row * TD);  // 1250 vec4
    float acc[8];
#pragma unroll
    for (int j = 0; j < 8; j++) acc[j] = 0.f;
    for (int v = tid; v < 1250; v += 256) {
        float4 xv = xrow[v];
        const float4* w = (const float4*)(We1 + (size_t)v * 32);
        float xc[4] = {xv.x, xv.y, xv.z, xv.w};
#pragma unroll
        for (int c = 0; c < 4; c++) {
            float4 wa = w[c * 2], wb = w[c * 2 + 1];
            acc[0] += xc[c] * wa.x; acc[1] += xc[c] * wa.y;
            acc[2] += xc[c] * wa.z; acc[3] += xc[c] * wa.w;
            acc[4] += xc[c] * wb.x; acc[5] += xc[c] * wb.y;
            acc[6] += xc[c] * wb.z; acc[7] += xc[c] * wb.w;
        }
    }
#pragma unroll
    for (int j = 0; j < 8; j++) red[j][tid] = acc[j];
    __syncthreads();
    for (int s = 128; s > 0; s >>= 1) {
        if (tid < s) {
#pragma unroll
            for (int j = 0; j < 8; j++) red[j][tid] += red[j][tid + s];
        }
        __syncthreads();
    }
    if (tid < 8) t1[tid] = fmaxf(red[tid][0] + be1[tid], 0.f);
    __syncthreads();
    if (tid < 4) {
        float z = be2[tid];
#pragma unroll
        for (int k = 0; k < 8; k++) z += t1[k] * We2[k * 4 + tid];
        z_text[row * 4 + tid] = fmaxf(z, 0.f);
    }
}

__device__ void role_decode(int row, int tid, const float* __restrict__ zsrc, int zstride,
                            const float* __restrict__ Wd1, const float* __restrict__ bd1,
                            const float* __restrict__ Wd2, const float* __restrict__ bd2,
                            float* __restrict__ xhat) {
    float zz[4];
#pragma unroll
    for (int j = 0; j < 4; j++) zz[j] = zsrc[row * zstride + j];
    float t[8];
#pragma unroll
    for (int k = 0; k < 8; k++) {
        float s = bd1[k];
#pragma unroll
        for (int j = 0; j < 4; j++) s += zz[j] * Wd1[j * 8 + k];
        t[k] = fmaxf(s, 0.f);
    }
    float4* orow = (float4*)(xhat + (size_t)row * TD);  // 1250 vec4
    for (int c4 = tid; c4 < 1250; c4 += 256) {
        float4 s = *(const float4*)(bd2 + c4 * 4);
#pragma unroll
        for (int k = 0; k < 8; k++) {
            float4 w = *(const float4*)(Wd2 + (size_t)k * TD + c4 * 4);
            s.x += t[k] * w.x; s.y += t[k] * w.y;
            s.z += t[k] * w.z; s.w += t[k] * w.w;
        }
        s.x = 1.f / (1.f + expf(-s.x));
        s.y = 1.f / (1.f + expf(-s.y));
        s.z = 1.f / (1.f + expf(-s.z));
        s.w = 1.f / (1.f + expf(-s.w));
        orow[c4] = s;
    }
}

__device__ void role_g1(int gid, int tid, const unsigned int* __restrict__ indptr,
                        const int* __restrict__ csr, const float* __restrict__ h0g,
                        const float* __restrict__ dinv, const float* __restrict__ bg1,
                        const float* __restrict__ Wg2, float* __restrict__ h2g) {
    __shared__ float W[32];
    __shared__ float b1[8];
    __shared__ float h1s[4][8];
    if (tid < 32) W[tid] = Wg2[tid];
    if (tid < 8) b1[tid] = bg1[tid];
    __syncthreads();
    int wid = tid >> 6, lane = tid & 63;
    int i = gid * 4 + wid;
    if (i < NN) {
        int beg = indptr[i], end = indptr[i + 1];
        int f = lane & 7;
        float a = 0.f;
        for (int k = beg + (lane >> 3); k < end; k += 8)
            a += h0g[(size_t)csr[k] * 8 + f];
        a += __shfl_xor(a, 8, 64);
        a += __shfl_xor(a, 16, 64);
        a += __shfl_xor(a, 32, 64);
        if (lane < 8) {
            float di = dinv[i];
            h1s[wid][f] = fmaxf(di * (a + h0g[(size_t)i * 8 + f]) + b1[f], 0.f);
        }
    }
    __syncthreads();
    if (i < NN && lane < 4) {
        float di = dinv[i];
        float s = 0.f;
#pragma unroll
        for (int k = 0; k < 8; k++) s += h1s[wid][k] * W[k * 4 + lane];
        h2g[(size_t)i * 4 + lane] = di * s;
    }
}

// ================= kernels =================
// fat1: rank (3125) || encode (4096); grid 7221. Dynamic LDS = ws-tier probe.
extern __shared__ char dyn_probe[];
__global__ __launch_bounds__(256) void k_fat1(
    const int* __restrict__ edge, const int* __restrict__ flag,
    unsigned int* __restrict__ deg, unsigned int* __restrict__ rnk,
    const float* __restrict__ text,
    const float* __restrict__ We1, const float* __restrict__ be1,
    const float* __restrict__ We2, const float* __restrict__ be2,
    float* __restrict__ z_text)
{
    int bid = blockIdx.x, tid = threadIdx.x;
    if (bid < 6250) {
        if (bid & 1) role_enc(bid >> 1, tid, text, We1, be1, We2, be2, z_text);
        else role_rank(bid >> 1, tid, edge, flag, deg, rnk);
    } else {
        role_enc(3125 + (bid - 6250), tid, text, We1, be1, We2, be2, z_text);
    }
}

// ---------------- post-rank node pass: dinv + per-block degree sums + batch boundaries ----
__global__ void kA_all(const unsigned int* __restrict__ deg, float* __restrict__ dinv,
                       unsigned int* __restrict__ bsum, const int* __restrict__ batch,
                       const int* __restrict__ flag, unsigned int* __restrict__ bnd) {
    __shared__ unsigned int s[256];
    int tid = threadIdx.x;
    int i = blockIdx.x * 256 + tid;
    unsigned int c = 0u;
    if (i < NN) {
        unsigned int u = deg[i];
        dinv[i] = rsqrtf((float)u);
        c = u - 1u;
        int fg = *flag;
        int b = fg ? batch[2 * i] : batch[i];
        int bp = (i == 0) ? -1 : (fg ? batch[2 * (i - 1)] : batch[i - 1]);
        for (int bb = bp + 1; bb <= b; bb++) bnd[bb] = (unsigned int)i;
        if (i == NN - 1)
            for (int bb = b + 1; bb <= BB; bb++) bnd[bb] = (unsigned int)NN;
    }
    s[tid] = c;
    __syncthreads();
    for (int st = 128; st > 0; st >>= 1) {
        if (tid < st) s[tid] += s[tid + st];
        __syncthreads();
    }
    if (tid == 0) bsum[blockIdx.x] = s[0];
}

__global__ void kB_scanblocks(const unsigned int* __restrict__ bsum, unsigned int* __restrict__ bpre,
                              unsigned int* __restrict__ indptr) {
    __shared__ unsigned int s[1024];
    int t = threadIdx.x;
    s[t] = (t < NBK) ? bsum[t] : 0u;
    __syncthreads();
    for (int off = 1; off < 1024; off <<= 1) {
        unsigned int v = (t >= off) ? s[t - off] : 0u;
        __syncthreads();
        s[t] += v;
        __syncthreads();
    }
    if (t < NBK) bpre[t] = (t == 0) ? 0u : s[t - 1];
    if (t == 0) indptr[NN] = EE;
}

__global__ void kC_indptr(const unsigned int* __restrict__ deg, const unsigned int* __restrict__ bpre,
                          unsigned int* __restrict__ indptr) {
    __shared__ unsigned int s[256];
    int tid = threadIdx.x;
    int i = blockIdx.x * 256 + tid;
    unsigned int c = (i < NN) ? (deg[i] - 1u) : 0u;
    s[tid] = c;
    __syncthreads();
    for (int off = 1; off < 256; off <<= 1) {
        unsigned int v = (tid >= off) ? s[tid - off] : 0u;
        __syncthreads();
        s[tid] += v;
        __syncthreads();
    }
    if (i < NN) indptr[i] = bpre[blockIdx.x] + s[tid] - c;  // exclusive
}

// place: 4 edges/thread (6250 blocks, exact) — round-9 proven form
__global__ __launch_bounds__(256) void k_place(
    const int* __restrict__ edge, const int* __restrict__ flag,
    const unsigned int* __restrict__ indptr, const unsigned int* __restrict__ rnk,
    int* __restrict__ csr)
{
    int f = *flag;
    int base = blockIdx.x * 1024 + threadIdx.x;
    int s[4], d[4];
#pragma unroll
    for (int k = 0; k < 4; k++) {
        int e = base + k * 256;
        s[k] = f ? edge[2 * e] : edge[e];
        d[k] = f ? edge[2 * (EE + e)] : edge[EE + e];
    }
    unsigned int rr[4];
#pragma unroll
    for (int k = 0; k < 4; k++) rr[k] = rnk[base + k * 256];
    unsigned int ip[4];
#pragma unroll
    for (int k = 0; k < 4; k++) ip[k] = indptr[d[k]];
#pragma unroll
    for (int k = 0; k < 4; k++) csr[ip[k] + rr[k] - 1u] = s[k];
}

// h0g = dinv * (node_x @ Wg1)
__global__ __launch_bounds__(256) void k_gcn1_mm(
    const float* __restrict__ nodex, const float* __restrict__ Wg1,
    const float* __restrict__ dinv, float* __restrict__ h0g)
{
    __shared__ float W[1024];
    int tid = threadIdx.x;
    for (int i = tid; i < 1024; i += 256) W[i] = Wg1[i];
    __syncthreads();
    int row = blockIdx.x * 256 + tid;
    if (row >= NN) return;
    const float4* xr = (const float4*)(nodex + (size_t)row * 128);
    float acc[8];
#pragma unroll
    for (int j = 0; j < 8; j++) acc[j] = 0.f;
#pragma unroll 8
    for (int c = 0; c < 32; c++) {
        float4 v = xr[c];
        const float* wr = &W[c * 32];
#pragma unroll
        for (int j = 0; j < 8; j++)
            acc[j] += v.x * wr[j] + v.y * wr[8 + j] + v.z * wr[16 + j] + v.w * wr[24 + j];
    }
    float di = dinv[row];
    float* o = h0g + (size_t)row * 8;
#pragma unroll
    for (int j = 0; j < 8; j++) o[j] = di * acc[j];
}

// tier B gather1
__global__ __launch_bounds__(256) void k_g1(
    const unsigned int* __restrict__ indptr, const int* __restrict__ csr,
    const float* __restrict__ h0g, const float* __restrict__ dinv,
    const float* __restrict__ bg1, const float* __restrict__ Wg2,
    float* __restrict__ h2g)
{
    role_g1(blockIdx.x, threadIdx.x, indptr, csr, h0g, dinv, bg1, Wg2, h2g);
}

// tier A gather1 || decode: grid 54096 (g1 50000 + dec 4096)
__global__ __launch_bounds__(256) void k_g1_dec(
    const unsigned int* __restrict__ indptr, const int* __restrict__ csr,
    const float* __restrict__ h0g, const float* __restrict__ dinv,
    const float* __restrict__ bg1, const float* __restrict__ Wg2,
    float* __restrict__ h2g, const float* __restrict__ z_text,
    const float* __restrict__ Wd1, const float* __restrict__ bd1,
    const float* __restrict__ Wd2, const float* __restrict__ bd2,
    float* __restrict__ xhat)
{
    int bid = blockIdx.x, tid = threadIdx.x;
    if (bid < 8192) {
        if (bid & 1) role_decode(bid >> 1, tid, z_text, 4, Wd1, bd1, Wd2, bd2, xhat);
        else role_g1(bid >> 1, tid, indptr, csr, h0g, dinv, bg1, Wg2, h2g);
    } else {
        role_g1(bid - 4096, tid, indptr, csr, h0g, dinv, bg1, Wg2, h2g);
    }
}

// tier B standalone decode (runs last; reads out_z stride 8)
__global__ __launch_bounds__(256) void k_dec(
    const float* __restrict__ zsrc,
    const float* __restrict__ Wd1, const float* __restrict__ bd1,
    const float* __restrict__ Wd2, const float* __restrict__ bd2,
    float* __restrict__ xhat)
{
    role_decode(blockIdx.x, threadIdx.x, zsrc, 8, Wd1, bd1, Wd2, bd2, xhat);
}

__global__ __launch_bounds__(256) void k_gather2(
    const unsigned int* __restrict__ indptr, const int* __restrict__ csr_src,
    const float* __restrict__ h2g, const float* __restrict__ dinv,
    const float* __restrict__ bg2, float* __restrict__ h2f)
{
    __shared__ float b2[4];
    int tid = threadIdx.x;
    if (tid < 4) b2[tid] = bg2[tid];
    __syncthreads();
    int wid = tid >> 6, lane = tid & 63;
    int i = blockIdx.x * 4 + wid;
    if (i >= NN) return;
    int beg = indptr[i], end = indptr[i + 1];
    int f = lane & 3;
    float a = 0.f;
    for (int k = beg + (lane >> 2); k < end; k += 16)
        a += h2g[(size_t)csr_src[k] * 4 + f];
    a += __shfl_xor(a, 4, 64);
    a += __shfl_xor(a, 8, 64);
    a += __shfl_xor(a, 16, 64);
    a += __shfl_xor(a, 32, 64);
    if (lane < 4) {
        float di = dinv[i];
        h2f[(size_t)i * 4 + f] = di * (a + h2g[(size_t)i * 4 + f]) + b2[f];
    }
}

__global__ __launch_bounds__(256) void k_final(
    const float* __restrict__ h2f, const unsigned int* __restrict__ bnd,
    const float* __restrict__ z_text, const float* __restrict__ Wc,
    const float* __restrict__ bc, float* __restrict__ out_logits,
    float* __restrict__ out_z)
{
    __shared__ float red[256][4];
    int g = blockIdx.x, tid = threadIdx.x;
    int lo = bnd[g], hi = bnd[g + 1];
    float a0 = 0.f, a1 = 0.f, a2 = 0.f, a3 = 0.f;
    for (int i = lo + tid; i < hi; i += 256) {
        float4 v = *(const float4*)(h2f + (size_t)i * 4);
        a0 += v.x; a1 += v.y; a2 += v.z; a3 += v.w;
    }
    red[tid][0] = a0; red[tid][1] = a1; red[tid][2] = a2; red[tid][3] = a3;
    __syncthreads();
    for (int s = 128; s > 0; s >>= 1) {
        if (tid < s) {
            red[tid][0] += red[tid + s][0]; red[tid][1] += red[tid + s][1];
            red[tid][2] += red[tid + s][2]; red[tid][3] += red[tid + s][3];
        }
        __syncthreads();
    }
    if (tid == 0) {
        float c = (float)(hi - lo);
        c = fmaxf(c, 1.f);
        float z8[8];
#pragma unroll
        for (int j = 0; j < 4; j++) z8[j] = z_text[g * 4 + j];
#pragma unroll
        for (int j = 0; j < 4; j++) z8[4 + j] = red[0][j] / c;
        float l = bc[0];
#pragma unroll
        for (int k = 0; k < 8; k++) l += z8[k] * Wc[k];
        out_logits[g] = l;
#pragma unroll
        for (int k = 0; k < 8; k++) out_z[g * 8 + k] = z8[k];
    }
}

extern "C" void kernel_launch(void* const* d_in, const int* in_sizes, int n_in,
                              void* d_out, int out_size, void* d_ws, size_t ws_size,
                              hipStream_t stream) {
    const float* text  = (const float*)d_in[0];
    const float* nodex = (const float*)d_in[1];
    const int* edge    = (const int*)d_in[2];
    const int* batch   = (const int*)d_in[3];
    const float* We1 = (const float*)d_in[4];
    const float* be1 = (const float*)d_in[5];
    const float* We2 = (const float*)d_in[6];
    const float* be2 = (const float*)d_in[7];
    const float* Wd1 = (const float*)d_in[8];
    const float* bd1 = (const float*)d_in[9];
    const float* Wd2 = (const float*)d_in[10];
    const float* bd2 = (const float*)d_in[11];
    const float* Wg1 = (const float*)d_in[12];
    const float* bg1 = (const float*)d_in[13];
    const float* Wg2 = (const float*)d_in[14];
    const float* bg2 = (const float*)d_in[15];
    const float* Wc  = (const float*)d_in[16];
    const float* bc  = (const float*)d_in[17];

    float* out_xhat   = (float*)d_out;
    float* out_logits = out_xhat + (size_t)BB * TD;
    float* out_z      = out_logits + BB;

    const bool use_ws = (ws_size >= WS_NEED);

    float *h0g, *h2g, *h2f, *dinv, *z_text;
    unsigned int *deg, *indptr, *rnk, *bsum, *bpre, *bnd;
    int *csr, *flag;

    if (use_ws) {
        // Tier A: gather-live set in d_ws (survives decode overwriting d_out x_hat).
        char* w = (char*)d_ws;
        h0g    = (float*)(w + 0);               //  6,400,000
        h2g    = (float*)(w + 6400000);         //  3,200,000
        h2f    = (float*)(w + 9600000);         //  3,200,000
        dinv   = (float*)(w + 12800000);        //    800,000
        indptr = (unsigned int*)(w + 13600000); //    800,004
        csr    = (int*)(w + 14400004);          // 25,600,000
        z_text = (float*)(w + 40000004);        //     65,536
        bnd    = (unsigned int*)(w + 40065540); //     16,388
        flag   = (int*)(w + 40081928);          //          4 -> 40,081,932
        // Build-dead set in d_out x_hat region (dead before decode writes):
        char* o = (char*)d_out;
        rnk  = (unsigned int*)(o + 0);          // 25,600,000 (dead after k_place)
        deg  = (unsigned int*)(o + 25600000);   //    800,000 (dead after kC)
        bsum = (unsigned int*)(o + 26400000);
        bpre = (unsigned int*)(o + 26403128);
    } else {
        // Tier B: exact round-9 proven layout; decode runs last.
        char* o = (char*)d_out;
        h0g    = (float*)(o + 0);
        h2g    = (float*)(o + 6400000);
        h2f    = (float*)(o + 9600000);
        dinv   = (float*)(o + 12800000);
        deg    = (unsigned int*)(o + 13600000);
        indptr = (unsigned int*)(o + 14400000);
        rnk    = (unsigned int*)(o + 15200004);
        csr    = (int*)(o + 40800004);
        bsum   = (unsigned int*)(o + 66400004);
        bpre   = (unsigned int*)(o + 66403132);
        z_text = (float*)(o + 66406260);
        bnd    = (unsigned int*)(o + 66471796);
        flag   = (int*)(o + 66488184);
    }

    k_init<<<NBK, 256, 0, stream>>>(edge, deg, flag);
    // dynamic-LDS tier probe: Tier A -> LDS_Block_Size 8704+1024, Tier B -> 8704
    k_fat1<<<7221, 256, use_ws ? 1024 : 0, stream>>>(edge, flag, deg, rnk,
                                                     text, We1, be1, We2, be2, z_text);
    kA_all<<<NBK, 256, 0, stream>>>(deg, dinv, bsum, batch, flag, bnd);
    kB_scanblocks<<<1, 1024, 0, stream>>>(bsum, bpre, indptr);
    kC_indptr<<<NBK, 256, 0, stream>>>(deg, bpre, indptr);
    k_place<<<6250, 256, 0, stream>>>(edge, flag, indptr, rnk, csr);
    k_gcn1_mm<<<NBK, 256, 0, stream>>>(nodex, Wg1, dinv, h0g);

    if (use_ws) {
        k_g1_dec<<<54096, 256, 0, stream>>>(indptr, csr, h0g, dinv, bg1, Wg2, h2g,
                                            z_text, Wd1, bd1, Wd2, bd2, out_xhat);
    } else {
        k_g1<<<(NN + 3) / 4, 256, 0, stream>>>(indptr, csr, h0g, dinv, bg1, Wg2, h2g);
    }

    k_gather2<<<(NN + 3) / 4, 256, 0, stream>>>(indptr, csr, h2g, dinv, bg2, h2f);
    k_final<<<BB, 256, 0, stream>>>(h2f, bnd, z_text, Wc, bc, out_logits, out_z);

    if (!use_ws) {
        k_dec<<<BB, 256, 0, stream>>>(out_z, Wd1, bd1, Wd2, bd2, out_xhat);
    }
}

// Round 15
// 708.996 us; speedup vs baseline: 1.5045x; 1.0499x over previous
//
#include <hip/hip_runtime.h>

#define BB 4096
#define TD 5000
#define NN 200000
#define EE 6400000
#define NBK 782  // ceil(NN/256)
#define WS_NEED 32081932ull

// ---------------- init: deg=1 everywhere; block 0 also detects edge dtype ----------------
__global__ void k_init(const int* __restrict__ e, unsigned int* __restrict__ deg,
                       int* __restrict__ flag) {
    int i = blockIdx.x * 256 + threadIdx.x;
    if (i < NN) deg[i] = 1u;  // self loop
    if (blockIdx.x == 0) {
        __shared__ int r[256];
        int tid = threadIdx.x;
        int acc = 0;
        for (int k = tid; k < 4096; k += 256) acc |= e[2 * k + 1];
        r[tid] = acc;
        __syncthreads();
        for (int s = 128; s > 0; s >>= 1) {
            if (tid < s) r[tid] |= r[tid + s];
            __syncthreads();
        }
        if (tid == 0) *flag = (r[0] == 0) ? 1 : 0;
    }
}

// ================= device roles =================
__device__ void role_rank(int rid, int tid, const int* __restrict__ edge,
                          const int* __restrict__ flag, unsigned int* __restrict__ deg,
                          unsigned int* __restrict__ rnk) {
    int f = *flag;
    int base = rid * 2048 + tid;
    int d[8];
#pragma unroll
    for (int k = 0; k < 8; k++) {
        int e = base + k * 256;
        d[k] = f ? edge[2 * (EE + e)] : edge[EE + e];
    }
    unsigned int rr[8];
#pragma unroll
    for (int k = 0; k < 8; k++) rr[k] = atomicAdd(&deg[d[k]], 1u);
#pragma unroll
    for (int k = 0; k < 8; k++) rnk[base + k * 256] = rr[k];
}

__device__ void role_enc(int row, int tid, const float* __restrict__ text,
                         const float* __restrict__ We1, const float* __restrict__ be1,
                         const float* __restrict__ We2, const float* __restrict__ be2,
                         float* __restrict__ z_text) {
    __shared__ float red[8][256];
    __shared__ float t1[8];
    const float4* xrow = (const float4*)(text + (size_t)row * TD);  // 1250 vec4
    float acc[8];
#pragma unroll
    for (int j = 0; j < 8; j++) acc[j] = 0.f;
    for (int v = tid; v < 1250; v += 256) {
        float4 xv = xrow[v];
        const float4* w = (const float4*)(We1 + (size_t)v * 32);
        float xc[4] = {xv.x, xv.y, xv.z, xv.w};
#pragma unroll
        for (int c = 0; c < 4; c++) {
            float4 wa = w[c * 2], wb = w[c * 2 + 1];
            acc[0] += xc[c] * wa.x; acc[1] += xc[c] * wa.y;
            acc[2] += xc[c] * wa.z; acc[3] += xc[c] * wa.w;
            acc[4] += xc[c] * wb.x; acc[5] += xc[c] * wb.y;
            acc[6] += xc[c] * wb.z; acc[7] += xc[c] * wb.w;
        }
    }
#pragma unroll
    for (int j = 0; j < 8; j++) red[j][tid] = acc[j];
    __syncthreads();
    for (int s = 128; s > 0; s >>= 1) {
        if (tid < s) {
#pragma unroll
            for (int j = 0; j < 8; j++) red[j][tid] += red[j][tid + s];
        }
        __syncthreads();
    }
    if (tid < 8) t1[tid] = fmaxf(red[tid][0] + be1[tid], 0.f);
    __syncthreads();
    if (tid < 4) {
        float z = be2[tid];
#pragma unroll
        for (int k = 0; k < 8; k++) z += t1[k] * We2[k * 4 + tid];
        z_text[row * 4 + tid] = fmaxf(z, 0.f);
    }
}

__device__ void role_decode(int row, int tid, const float* __restrict__ zsrc, int zstride,
                            const float* __restrict__ Wd1, const float* __restrict__ bd1,
                            const float* __restrict__ Wd2, const float* __restrict__ bd2,
                            float* __restrict__ xhat) {
    float zz[4];
#pragma unroll
    for (int j = 0; j < 4; j++) zz[j] = zsrc[row * zstride + j];
    float t[8];
#pragma unroll
    for (int k = 0; k < 8; k++) {
        float s = bd1[k];
#pragma unroll
        for (int j = 0; j < 4; j++) s += zz[j] * Wd1[j * 8 + k];
        t[k] = fmaxf(s, 0.f);
    }
    float4* orow = (float4*)(xhat + (size_t)row * TD);  // 1250 vec4
    for (int c4 = tid; c4 < 1250; c4 += 256) {
        float4 s = *(const float4*)(bd2 + c4 * 4);
#pragma unroll
        for (int k = 0; k < 8; k++) {
            float4 w = *(const float4*)(Wd2 + (size_t)k * TD + c4 * 4);
            s.x += t[k] * w.x; s.y += t[k] * w.y;
            s.z += t[k] * w.z; s.w += t[k] * w.w;
        }
        s.x = 1.f / (1.f + expf(-s.x));
        s.y = 1.f / (1.f + expf(-s.y));
        s.z = 1.f / (1.f + expf(-s.z));
        s.w = 1.f / (1.f + expf(-s.w));
        orow[c4] = s;
    }
}

__device__ void role_place(int pid, int tid, const int* __restrict__ edge,
                           const int* __restrict__ flag,
                           const unsigned int* __restrict__ indptr,
                           const unsigned int* __restrict__ rnk, int* __restrict__ csr) {
    int f = *flag;
    int base = pid * 1024 + tid;
    int s[4], d[4];
#pragma unroll
    for (int k = 0; k < 4; k++) {
        int e = base + k * 256;
        s[k] = f ? edge[2 * e] : edge[e];
        d[k] = f ? edge[2 * (EE + e)] : edge[EE + e];
    }
    unsigned int rr[4];
#pragma unroll
    for (int k = 0; k < 4; k++) rr[k] = rnk[base + k * 256];
    unsigned int ip[4];
#pragma unroll
    for (int k = 0; k < 4; k++) ip[k] = indptr[d[k]];
#pragma unroll
    for (int k = 0; k < 4; k++) csr[ip[k] + rr[k] - 1u] = s[k];
}

// h0g (fp16) = dinv * (node_x @ Wg1)
__device__ void role_mm(int mid, int tid, const float* __restrict__ nodex,
                        const float* __restrict__ Wg1, const float* __restrict__ dinv,
                        _Float16* __restrict__ h0g) {
    __shared__ float W[1024];
    for (int i = tid; i < 1024; i += 256) W[i] = Wg1[i];
    __syncthreads();
    int row = mid * 256 + tid;
    if (row >= NN) return;
    const float4* xr = (const float4*)(nodex + (size_t)row * 128);
    float acc[8];
#pragma unroll
    for (int j = 0; j < 8; j++) acc[j] = 0.f;
#pragma unroll 8
    for (int c = 0; c < 32; c++) {
        float4 v = xr[c];
        const float* wr = &W[c * 32];
#pragma unroll
        for (int j = 0; j < 8; j++)
            acc[j] += v.x * wr[j] + v.y * wr[8 + j] + v.z * wr[16 + j] + v.w * wr[24 + j];
    }
    float di = dinv[row];
    _Float16* o = h0g + (size_t)row * 8;
#pragma unroll
    for (int j = 0; j < 8; j++) o[j] = (_Float16)(di * acc[j]);
}

__device__ void role_g1(int gid, int tid, const unsigned int* __restrict__ indptr,
                        const int* __restrict__ csr, const _Float16* __restrict__ h0g,
                        const float* __restrict__ dinv, const float* __restrict__ bg1,
                        const float* __restrict__ Wg2, _Float16* __restrict__ h2g) {
    __shared__ float W[32];
    __shared__ float b1[8];
    __shared__ float h1s[4][8];
    if (tid < 32) W[tid] = Wg2[tid];
    if (tid < 8) b1[tid] = bg1[tid];
    __syncthreads();
    int wid = tid >> 6, lane = tid & 63;
    int i = gid * 4 + wid;
    if (i < NN) {
        int beg = indptr[i], end = indptr[i + 1];
        int f = lane & 7;
        float a = 0.f;
        for (int k = beg + (lane >> 3); k < end; k += 8)
            a += (float)h0g[(size_t)csr[k] * 8 + f];
        a += __shfl_xor(a, 8, 64);
        a += __shfl_xor(a, 16, 64);
        a += __shfl_xor(a, 32, 64);
        if (lane < 8) {
            float di = dinv[i];
            h1s[wid][f] = fmaxf(di * (a + (float)h0g[(size_t)i * 8 + f]) + b1[f], 0.f);
        }
    }
    __syncthreads();
    if (i < NN && lane < 4) {
        float di = dinv[i];
        float s = 0.f;
#pragma unroll
        for (int k = 0; k < 8; k++) s += h1s[wid][k] * W[k * 4 + lane];
        h2g[(size_t)i * 4 + lane] = (_Float16)(di * s);
    }
}

// ================= kernels =================
// fat1: rank (3125) || encode (4096); grid 7221. Dynamic LDS = ws-tier probe.
__global__ __launch_bounds__(256) void k_fat1(
    const int* __restrict__ edge, const int* __restrict__ flag,
    unsigned int* __restrict__ deg, unsigned int* __restrict__ rnk,
    const float* __restrict__ text,
    const float* __restrict__ We1, const float* __restrict__ be1,
    const float* __restrict__ We2, const float* __restrict__ be2,
    float* __restrict__ z_text)
{
    int bid = blockIdx.x, tid = threadIdx.x;
    if (bid < 6250) {
        if (bid & 1) role_enc(bid >> 1, tid, text, We1, be1, We2, be2, z_text);
        else role_rank(bid >> 1, tid, edge, flag, deg, rnk);
    } else {
        role_enc(3125 + (bid - 6250), tid, text, We1, be1, We2, be2, z_text);
    }
}

// post-rank node pass: dinv + per-block degree sums + batch boundaries
__global__ void kA_all(const unsigned int* __restrict__ deg, float* __restrict__ dinv,
                       unsigned int* __restrict__ bsum, const int* __restrict__ batch,
                       const int* __restrict__ flag, unsigned int* __restrict__ bnd) {
    __shared__ unsigned int s[256];
    int tid = threadIdx.x;
    int i = blockIdx.x * 256 + tid;
    unsigned int c = 0u;
    if (i < NN) {
        unsigned int u = deg[i];
        dinv[i] = rsqrtf((float)u);
        c = u - 1u;
        int fg = *flag;
        int b = fg ? batch[2 * i] : batch[i];
        int bp = (i == 0) ? -1 : (fg ? batch[2 * (i - 1)] : batch[i - 1]);
        for (int bb = bp + 1; bb <= b; bb++) bnd[bb] = (unsigned int)i;
        if (i == NN - 1)
            for (int bb = b + 1; bb <= BB; bb++) bnd[bb] = (unsigned int)NN;
    }
    s[tid] = c;
    __syncthreads();
    for (int st = 128; st > 0; st >>= 1) {
        if (tid < st) s[tid] += s[tid + st];
        __syncthreads();
    }
    if (tid == 0) bsum[blockIdx.x] = s[0];
}

__global__ void kB_scanblocks(const unsigned int* __restrict__ bsum, unsigned int* __restrict__ bpre,
                              unsigned int* __restrict__ indptr) {
    __shared__ unsigned int s[1024];
    int t = threadIdx.x;
    s[t] = (t < NBK) ? bsum[t] : 0u;
    __syncthreads();
    for (int off = 1; off < 1024; off <<= 1) {
        unsigned int v = (t >= off) ? s[t - off] : 0u;
        __syncthreads();
        s[t] += v;
        __syncthreads();
    }
    if (t < NBK) bpre[t] = (t == 0) ? 0u : s[t - 1];
    if (t == 0) indptr[NN] = EE;
}

__global__ void kC_indptr(const unsigned int* __restrict__ deg, const unsigned int* __restrict__ bpre,
                          unsigned int* __restrict__ indptr) {
    __shared__ unsigned int s[256];
    int tid = threadIdx.x;
    int i = blockIdx.x * 256 + tid;
    unsigned int c = (i < NN) ? (deg[i] - 1u) : 0u;
    s[tid] = c;
    __syncthreads();
    for (int off = 1; off < 256; off <<= 1) {
        unsigned int v = (tid >= off) ? s[tid - off] : 0u;
        __syncthreads();
        s[tid] += v;
        __syncthreads();
    }
    if (i < NN) indptr[i] = bpre[blockIdx.x] + s[tid] - c;  // exclusive
}

// fat2: place (6250) || mm (782); grid 7032 — round-9 proven structure
__global__ __launch_bounds__(256) void k_fat2(
    const int* __restrict__ edge, const int* __restrict__ flag,
    const unsigned int* __restrict__ indptr, const unsigned int* __restrict__ rnk,
    int* __restrict__ csr, const float* __restrict__ nodex,
    const float* __restrict__ Wg1, const float* __restrict__ dinv,
    _Float16* __restrict__ h0g)
{
    int bid = blockIdx.x, tid = threadIdx.x;
    if (bid < 6250) role_place(bid, tid, edge, flag, indptr, rnk, csr);
    else role_mm(bid - 6250, tid, nodex, Wg1, dinv, h0g);
}

// tier B gather1
__global__ __launch_bounds__(256) void k_g1(
    const unsigned int* __restrict__ indptr, const int* __restrict__ csr,
    const _Float16* __restrict__ h0g, const float* __restrict__ dinv,
    const float* __restrict__ bg1, const float* __restrict__ Wg2,
    _Float16* __restrict__ h2g)
{
    role_g1(blockIdx.x, threadIdx.x, indptr, csr, h0g, dinv, bg1, Wg2, h2g);
}

// tier A gather1 || decode: grid 54096 (g1 50000 + dec 4096)
__global__ __launch_bounds__(256) void k_g1_dec(
    const unsigned int* __restrict__ indptr, const int* __restrict__ csr,
    const _Float16* __restrict__ h0g, const float* __restrict__ dinv,
    const float* __restrict__ bg1, const float* __restrict__ Wg2,
    _Float16* __restrict__ h2g, const float* __restrict__ z_text,
    const float* __restrict__ Wd1, const float* __restrict__ bd1,
    const float* __restrict__ Wd2, const float* __restrict__ bd2,
    float* __restrict__ xhat)
{
    int bid = blockIdx.x, tid = threadIdx.x;
    if (bid < 8192) {
        if (bid & 1) role_decode(bid >> 1, tid, z_text, 4, Wd1, bd1, Wd2, bd2, xhat);
        else role_g1(bid >> 1, tid, indptr, csr, h0g, dinv, bg1, Wg2, h2g);
    } else {
        role_g1(bid - 4096, tid, indptr, csr, h0g, dinv, bg1, Wg2, h2g);
    }
}

// tier B standalone decode (runs last; reads out_z stride 8)
__global__ __launch_bounds__(256) void k_dec(
    const float* __restrict__ zsrc,
    const float* __restrict__ Wd1, const float* __restrict__ bd1,
    const float* __restrict__ Wd2, const float* __restrict__ bd2,
    float* __restrict__ xhat)
{
    role_decode(blockIdx.x, threadIdx.x, zsrc, 8, Wd1, bd1, Wd2, bd2, xhat);
}

__global__ __launch_bounds__(256) void k_gather2(
    const unsigned int* __restrict__ indptr, const int* __restrict__ csr_src,
    const _Float16* __restrict__ h2g, const float* __restrict__ dinv,
    const float* __restrict__ bg2, float* __restrict__ h2f)
{
    __shared__ float b2[4];
    int tid = threadIdx.x;
    if (tid < 4) b2[tid] = bg2[tid];
    __syncthreads();
    int wid = tid >> 6, lane = tid & 63;
    int i = blockIdx.x * 4 + wid;
    if (i >= NN) return;
    int beg = indptr[i], end = indptr[i + 1];
    int f = lane & 3;
    float a = 0.f;
    for (int k = beg + (lane >> 2); k < end; k += 16)
        a += (float)h2g[(size_t)csr_src[k] * 4 + f];
    a += __shfl_xor(a, 4, 64);
    a += __shfl_xor(a, 8, 64);
    a += __shfl_xor(a, 16, 64);
    a += __shfl_xor(a, 32, 64);
    if (lane < 4) {
        float di = dinv[i];
        h2f[(size_t)i * 4 + f] = di * (a + (float)h2g[(size_t)i * 4 + f]) + b2[f];
    }
}

__global__ __launch_bounds__(256) void k_final(
    const float* __restrict__ h2f, const unsigned int* __restrict__ bnd,
    const float* __restrict__ z_text, const float* __restrict__ Wc,
    const float* __restrict__ bc, float* __restrict__ out_logits,
    float* __restrict__ out_z)
{
    __shared__ float red[256][4];
    int g = blockIdx.x, tid = threadIdx.x;
    int lo = bnd[g], hi = bnd[g + 1];
    float a0 = 0.f, a1 = 0.f, a2 = 0.f, a3 = 0.f;
    for (int i = lo + tid; i < hi; i += 256) {
        float4 v = *(const float4*)(h2f + (size_t)i * 4);
        a0 += v.x; a1 += v.y; a2 += v.z; a3 += v.w;
    }
    red[tid][0] = a0; red[tid][1] = a1; red[tid][2] = a2; red[tid][3] = a3;
    __syncthreads();
    for (int s = 128; s > 0; s >>= 1) {
        if (tid < s) {
            red[tid][0] += red[tid + s][0]; red[tid][1] += red[tid + s][1];
            red[tid][2] += red[tid + s][2]; red[tid][3] += red[tid + s][3];
        }
        __syncthreads();
    }
    if (tid == 0) {
        float c = (float)(hi - lo);
        c = fmaxf(c, 1.f);
        float z8[8];
#pragma unroll
        for (int j = 0; j < 4; j++) z8[j] = z_text[g * 4 + j];
#pragma unroll
        for (int j = 0; j < 4; j++) z8[4 + j] = red[0][j] / c;
        float l = bc[0];
#pragma unroll
        for (int k = 0; k < 8; k++) l += z8[k] * Wc[k];
        out_logits[g] = l;
#pragma unroll
        for (int k = 0; k < 8; k++) out_z[g * 8 + k] = z8[k];
    }
}

extern "C" void kernel_launch(void* const* d_in, const int* in_sizes, int n_in,
                              void* d_out, int out_size, void* d_ws, size_t ws_size,
                              hipStream_t stream) {
    const float* text  = (const float*)d_in[0];
    const float* nodex = (const float*)d_in[1];
    const int* edge    = (const int*)d_in[2];
    const int* batch   = (const int*)d_in[3];
    const float* We1 = (const float*)d_in[4];
    const float* be1 = (const float*)d_in[5];
    const float* We2 = (const float*)d_in[6];
    const float* be2 = (const float*)d_in[7];
    const float* Wd1 = (const float*)d_in[8];
    const float* bd1 = (const float*)d_in[9];
    const float* Wd2 = (const float*)d_in[10];
    const float* bd2 = (const float*)d_in[11];
    const float* Wg1 = (const float*)d_in[12];
    const float* bg1 = (const float*)d_in[13];
    const float* Wg2 = (const float*)d_in[14];
    const float* bg2 = (const float*)d_in[15];
    const float* Wc  = (const float*)d_in[16];
    const float* bc  = (const float*)d_in[17];

    float* out_xhat   = (float*)d_out;
    float* out_logits = out_xhat + (size_t)BB * TD;
    float* out_z      = out_logits + BB;

    const bool use_ws = (ws_size >= WS_NEED);

    _Float16 *h0g, *h2g;
    float *h2f, *dinv, *z_text;
    unsigned int *deg, *indptr, *rnk, *bsum, *bpre, *bnd;
    int *csr, *flag;

    if (use_ws) {
        // Tier A: gather-live set in d_ws (survives decode overwriting d_out x_hat).
        char* w = (char*)d_ws;
        csr    = (int*)(w + 0);                   // 25,600,000
        h0g    = (_Float16*)(w + 25600000);       //  3,200,000 (fp16 N*8)
        h2f    = (float*)(w + 25600000);          //  3,200,000 alias (h0g dead after g1)
        h2g    = (_Float16*)(w + 28800000);       //  1,600,000 (fp16 N*4)
        dinv   = (float*)(w + 30400000);          //    800,000
        indptr = (unsigned int*)(w + 31200000);   //    800,004
        z_text = (float*)(w + 32000004);          //     65,536
        bnd    = (unsigned int*)(w + 32065540);   //     16,388
        flag   = (int*)(w + 32081928);            //          4 -> 32,081,932
        // Build-dead set in d_out x_hat region (dead before decode writes):
        char* o = (char*)d_out;
        rnk  = (unsigned int*)(o + 0);            // 25,600,000 (dead after fat2)
        deg  = (unsigned int*)(o + 25600000);     //    800,000 (dead after kC)
        bsum = (unsigned int*)(o + 26400000);
        bpre = (unsigned int*)(o + 26403128);
    } else {
        // Tier B: everything in d_out x_hat region; decode runs last.
        char* o = (char*)d_out;
        h0g    = (_Float16*)(o + 0);              // 3,200,000
        h2f    = (float*)(o + 0);                 // alias (h0g dead after g1)
        h2g    = (_Float16*)(o + 3200000);        // 1,600,000
        dinv   = (float*)(o + 4800000);           //   800,000
        deg    = (unsigned int*)(o + 5600000);    //   800,000
        indptr = (unsigned int*)(o + 6400000);    //   800,004
        rnk    = (unsigned int*)(o + 7200004);    // 25,600,000
        csr    = (int*)(o + 32800004);            // 25,600,000
        bsum   = (unsigned int*)(o + 58400004);
        bpre   = (unsigned int*)(o + 58403132);
        z_text = (float*)(o + 58406260);
        bnd    = (unsigned int*)(o + 58471796);
        flag   = (int*)(o + 58488184);            // ends 58,488,188 < 81,920,000
    }

    k_init<<<NBK, 256, 0, stream>>>(edge, deg, flag);
    // dynamic-LDS tier probe: Tier A -> LDS_Block_Size 8704+1024, Tier B -> 8704
    k_fat1<<<7221, 256, use_ws ? 1024 : 0, stream>>>(edge, flag, deg, rnk,
                                                     text, We1, be1, We2, be2, z_text);
    kA_all<<<NBK, 256, 0, stream>>>(deg, dinv, bsum, batch, flag, bnd);
    kB_scanblocks<<<1, 1024, 0, stream>>>(bsum, bpre, indptr);
    kC_indptr<<<NBK, 256, 0, stream>>>(deg, bpre, indptr);
    k_fat2<<<7032, 256, 0, stream>>>(edge, flag, indptr, rnk, csr,
                                     nodex, Wg1, dinv, h0g);

    if (use_ws) {
        k_g1_dec<<<54096, 256, 0, stream>>>(indptr, csr, h0g, dinv, bg1, Wg2, h2g,
                                            z_text, Wd1, bd1, Wd2, bd2, out_xhat);
    } else {
        k_g1<<<(NN + 3) / 4, 256, 0, stream>>>(indptr, csr, h0g, dinv, bg1, Wg2, h2g);
    }

    k_gather2<<<(NN + 3) / 4, 256, 0, stream>>>(indptr, csr, h2g, dinv, bg2, h2f);
    k_final<<<BB, 256, 0, stream>>>(h2f, bnd, z_text, Wc, bc, out_logits, out_z);

    if (!use_ws) {
        k_dec<<<BB, 256, 0, stream>>>(out_z, Wd1, bd1, Wd2, bd2, out_xhat);
    }
}